// Round 4
// baseline (115.670 us; speedup 1.0000x reference)
//
#include <hip/hip_runtime.h>

// YOLO-style loss, MI355X.
// loss = (2*sum((p_box - t_box)^2) + sum(mask ? CE : 0)) / 512
// channels: box = {0..3, 24..27}; cls = {8..27}; 4..7 unused.
// float4 chunks per 28-float cell: c4=0 box, c4=1 unused, c4=2..6 cls (20 floats),
// c4=6 doubles as box (24..27).
//
// Structure: coalesced load of everything into regs; coord computed inline
// (element-separable, p/t chunk pairs are thread-local); only cls chunks staged
// through a single 20 KB LDS buffer in two phases (p then t). Packed 80 B rows
// (20 floats/cell): read banks = (20*cell + 4*s) % 32 — 20c mod 32 cycles all 8
// multiples of 4 => uniform 8 accesses/bank = b128 minimum. No swizzle needed.

#define C_CLS 20
#define D_CH 28
#define BATCH_N 512
#define CELLS (BATCH_N * 28 * 28)     // 401408
#define BLOCK 256
#define CPB 256                       // cells per block
#define NBLOCKS (CELLS / CPB)         // 1568, exact

__global__ __launch_bounds__(BLOCK) void yolo_fused_kernel(
    const float* __restrict__ preds,
    const float* __restrict__ tgts,
    float* __restrict__ out)
{
    __shared__ float lds[CPB * C_CLS];   // 20 KB, reused for p then t
    __shared__ float sm[BLOCK / 64];

    const int tid = threadIdx.x;
    const size_t base = (size_t)blockIdx.x * (CPB * D_CH);
    const float4* gp = reinterpret_cast<const float4*>(preds + base);
    const float4* gt = reinterpret_cast<const float4*>(tgts + base);

    // ---- all global loads issued up-front, perfectly coalesced ----
    float4 vp[7], vt[7];
    #pragma unroll
    for (int k = 0; k < 7; ++k) vp[k] = gp[tid + BLOCK * k];
    #pragma unroll
    for (int k = 0; k < 7; ++k) vt[k] = gt[tid + BLOCK * k];

    // ---- coord loss inline: chunks with c4==0 or c4==6 (each thread has exactly
    //      one of each since 256 ≡ 4 (mod 7) walks all residues over k=0..6) ----
    float coord = 0.0f;
    #pragma unroll
    for (int k = 0; k < 7; ++k) {
        const int idx = tid + BLOCK * k;
        const int c4  = idx % 7;
        if (c4 == 0 || c4 == 6) {
            float dx = vp[k].x - vt[k].x; coord = fmaf(dx, dx, coord);
            float dy = vp[k].y - vt[k].y; coord = fmaf(dy, dy, coord);
            float dz = vp[k].z - vt[k].z; coord = fmaf(dz, dz, coord);
            float dw = vp[k].w - vt[k].w; coord = fmaf(dw, dw, coord);
        }
    }

    // ---- phase 1: stage pred cls chunks (c4 in 2..6), packed 80B rows ----
    #pragma unroll
    for (int k = 0; k < 7; ++k) {
        const int idx  = tid + BLOCK * k;
        const int cell = idx / 7;
        const int c4   = idx - cell * 7;
        if (c4 >= 2)
            *reinterpret_cast<float4*>(&lds[cell * C_CLS + (c4 - 2) * 4]) = vp[k];
    }
    __syncthreads();

    float pc[C_CLS];
    #pragma unroll
    for (int s = 0; s < 5; ++s) {
        float4 a = *reinterpret_cast<const float4*>(&lds[tid * C_CLS + s * 4]);
        pc[4*s+0] = a.x; pc[4*s+1] = a.y; pc[4*s+2] = a.z; pc[4*s+3] = a.w;
    }
    float m = pc[0];
    #pragma unroll
    for (int j = 1; j < C_CLS; ++j) m = fmaxf(m, pc[j]);
    float se = 0.0f;
    #pragma unroll
    for (int j = 0; j < C_CLS; ++j) se += __expf(pc[j] - m);
    __syncthreads();   // everyone done reading p before t overwrites

    // ---- phase 2: stage target cls chunks into the same buffer ----
    #pragma unroll
    for (int k = 0; k < 7; ++k) {
        const int idx  = tid + BLOCK * k;
        const int cell = idx / 7;
        const int c4   = idx - cell * 7;
        if (c4 >= 2)
            *reinterpret_cast<float4*>(&lds[cell * C_CLS + (c4 - 2) * 4]) = vt[k];
    }
    __syncthreads();

    float tsum = 0.0f;
    float tmax = -INFINITY;
    int   lab  = 0;
    #pragma unroll
    for (int s = 0; s < 5; ++s) {
        float4 a = *reinterpret_cast<const float4*>(&lds[tid * C_CLS + s * 4]);
        float c0 = a.x, c1 = a.y, c2 = a.z, c3 = a.w;
        tsum += c0 + c1 + c2 + c3;
        if (c0 > tmax) { tmax = c0; lab = 4*s+0; }   // ascending order => first-max
        if (c1 > tmax) { tmax = c1; lab = 4*s+1; }
        if (c2 > tmax) { tmax = c2; lab = 4*s+2; }
        if (c3 > tmax) { tmax = c3; lab = 4*s+3; }
    }
    float plab = pc[0];
    #pragma unroll
    for (int j = 1; j < C_CLS; ++j) plab = (lab == j) ? pc[j] : plab;
    float ce = -(plab - m - __logf(se));

    float loss = 2.0f * coord + ((tsum > 0.0f) ? ce : 0.0f);

    // ---- wave + block reduce, one atomic per block ----
    #pragma unroll
    for (int off = 32; off > 0; off >>= 1) loss += __shfl_down(loss, off, 64);

    const int wid  = tid >> 6;
    const int lane = tid & 63;
    if (lane == 0) sm[wid] = loss;
    __syncthreads();
    if (tid == 0) {
        float s = sm[0] + sm[1] + sm[2] + sm[3];
        atomicAdd(out, s * (1.0f / (float)BATCH_N));
    }
}

extern "C" void kernel_launch(void* const* d_in, const int* in_sizes, int n_in,
                              void* d_out, int out_size, void* d_ws, size_t ws_size,
                              hipStream_t stream)
{
    const float* preds = (const float*)d_in[0];
    const float* tgts  = (const float*)d_in[1];
    float* out = (float*)d_out;

    hipMemsetAsync(out, 0, (size_t)out_size * sizeof(float), stream);  // d_out poisoned 0xAA
    yolo_fused_kernel<<<NBLOCKS, BLOCK, 0, stream>>>(preds, tgts, out);
}